// Round 7
// baseline (261.645 us; speedup 1.0000x reference)
//
#include <hip/hip_runtime.h>

// ContextTokenModel — round 16: overlapped 8-row jobs -> 2 waves/SIMD.
// Cross-round evidence: krec0 is ~45 µs whether the loop has 36 MFMAs, 12
// MFMAs, or spills -> latency-bound at 1 wave/SIMD (~70% exposed stall).
// Fix: 2048 jobs of 8 rows (each wave computes a padded 16-row tile, rows
// 8jb..8jb+15 clamped, but writes only its low 8 rows). 2 independent
// waves/SIMD overlap each other's chain stalls; no barriers anywhere.
//  - krec0: r13 in-loop gatherX (PROJ regression reverted), wf weight frags.
//  - k3b:   r15 pipelined y-partials + same 8-row split.
//  - y0a stitching: store (nl<8) -> tile jb>>1 slot nl+8*(jb&1);
//    k3b reads per-lane tile R>>4 slot R&15.
// B=8192, T=21, D_in=160, H=32. Output fp32 [B,21,64] (fw|bw).

typedef __attribute__((ext_vector_type(8))) short short8;
typedef __attribute__((ext_vector_type(8))) __bf16 bf16x8;
typedef __attribute__((ext_vector_type(4))) float f32x4;
typedef unsigned short ushort_t;

// ---- bf16 cvt region (ushort offsets from ws+64) ----
#define U_TOKEMB  0             // 5000*128
#define U_TYPEMB  640000        // 5000*32
#define U_HOLE    800000        // 160
#define U_GKFW0   800160        // 192*64
#define U_GBFW0   812448        // 64
#define U_CKFW0   812512        // 192*32
#define U_CBFW0   818656        // 32
#define U_GKBW0   818688
#define U_GBBW0   830976
#define U_CKBW0   831040
#define U_CBBW0   837184
#define U_GKFW1   837216        // 96*64
#define U_GBFW1   843360
#define U_CKFW1   843424        // 96*32
#define U_CBFW1   846496
#define U_GKBW1   846528
#define U_GBBW1   852672
#define U_CKBW1   852736
#define U_CBBW1   855808
// cvt ends at 64 + 855840*2 = 1,711,744 B

#define Y0A_OFF   (4u << 20)    // y0a bf16 A-frags: uint4 [21*512][2][64] = 22,020,096 B
#define TYPF_OFF  (25u << 20)   // type-max bf16 A-frags: uint4 [20*512][64] = 10,485,760 B
#define WF_OFF    (37u << 20)   // swizzled weight B-frags: uint4 [108][64] = 110,592 B

__device__ __forceinline__ float bf2f(unsigned int u) {
  union { unsigned int i; float f; } v; v.i = u << 16; return v.f;
}
__device__ __forceinline__ unsigned short f2bf(float f) {
  unsigned int u = __float_as_uint(f);
  u += 0x7fffu + ((u >> 16) & 1u);
  return (unsigned short)(u >> 16);
}
__device__ __forceinline__ f32x4 mfma16(short8 a, short8 b, f32x4 c) {
  return __builtin_amdgcn_mfma_f32_16x16x32_bf16(
      __builtin_bit_cast(bf16x8, a), __builtin_bit_cast(bf16x8, b), c, 0, 0, 0);
}
__device__ __forceinline__ float sgm(float x) {
  x = fminf(fmaxf(x, -30.f), 30.f);
  return __fdividef(1.f, 1.f + __expf(-x));
}
__device__ __forceinline__ float tnh(float x) {
  x = fminf(fmaxf(x, -15.f), 15.f);
  float e = __expf(2.f * x);
  return (e - 1.f) * __fdividef(1.f, e + 1.f);
}

// ---------------------------------------------------------------------------
// k0 probes (validated in r8). flags[0]=fp32 floats; flags[1]=byte masks;
// flags[2]=types/mask slots swapped.
// ---------------------------------------------------------------------------
__global__ void k0_detect(const ushort_t* __restrict__ probe_f,
                          const unsigned* __restrict__ probe_m,
                          const unsigned* __restrict__ probe_t,
                          int* __restrict__ flags) {
  const int lane = threadIdx.x;  // 64
  int cnt = 0;
#pragma unroll
  for (int i = 0; i < 4; ++i) {
    unsigned e = ((unsigned)probe_f[lane + i * 64] >> 7) & 0xffu;
    if (e == 0u || (e >= 112u && e <= 134u)) cnt++;
  }
#pragma unroll
  for (int off = 32; off > 0; off >>= 1) cnt += __shfl_down(cnt, off, 64);
  const unsigned v = probe_m[lane];
  const unsigned long long bytelike =
      __ballot((v > 1u) && (v != 0x3F800000u) && ((v & 0xFEFEFEFEu) == 0u));
  const unsigned tv = probe_t[lane];
  const unsigned long long tlooksTypes =
      __ballot(!(tv == 0u || tv == 1u || tv == 0x3F800000u));
  if (lane == 0) {
    flags[0] = (cnt < 205) ? 1 : 0;
    flags[1] = bytelike ? 1 : 0;
    flags[2] = tlooksTypes ? 0 : 1;
  }
}

// ---------------------------------------------------------------------------
// kcvt: normalize all 19 float inputs to bf16 cvt region.
// ---------------------------------------------------------------------------
struct Cvt19 { const void* src[19]; int len[19]; int dst[19]; };

__global__ void kcvt(Cvt19 a, ushort_t* __restrict__ cvt, const int* __restrict__ flags) {
  const int fp32 = flags[0];
  int gid = blockIdx.x * blockDim.x + threadIdx.x;
#pragma unroll 1
  for (int s = 0; s < 19; ++s) {
    if (gid < a.len[s]) {
      cvt[a.dst[s] + gid] = fp32 ? f2bf(((const float*)a.src[s])[gid])
                                 : ((const ushort_t*)a.src[s])[gid];
      return;
    }
    gid -= a.len[s];
  }
}

// ---------------------------------------------------------------------------
// kswz: pre-swizzle all weight B-frags into per-lane uint4 layout (validated r14).
// L0 dir d: f<20: wg[kt=f>>2][tn=f&3]; 20..29: wc[kt=(f-20)>>1][tn=(f-20)&1];
// 30..33: wgh; 34..35: wch.  L1: f<12: wg; 12..17: wc.
// wf[(layer?72+d*18+f : d*36+f)*64+lane]
// ---------------------------------------------------------------------------
__global__ void kswz(const ushort_t* __restrict__ cvt, uint4* __restrict__ wf) {
  const int id = blockIdx.x * blockDim.x + threadIdx.x;
  if (id >= 108 * 64) return;
  const int frag = id >> 6, lane = id & 63;
  const int q = lane >> 4, nl = lane & 15;
  const int layer = (frag >= 72) ? 1 : 0;
  const int fr = layer ? frag - 72 : frag;
  const int nper = layer ? 18 : 36;
  const int d = fr / nper;
  const int f = fr - d * nper;
  const ushort_t* gk = layer ? (cvt + (d ? U_GKBW1 : U_GKFW1))
                             : (cvt + (d ? U_GKBW0 : U_GKFW0));
  const ushort_t* ck = layer ? (cvt + (d ? U_CKBW1 : U_CKFW1))
                             : (cvt + (d ? U_CKBW0 : U_CKFW0));
  const ushort_t* src; int row0, colw, coloff;
  if (!layer) {
    if (f < 20)      { src = gk; row0 = (f >> 2) * 32; colw = 64; coloff = (f & 3) * 16; }
    else if (f < 30) { int g = f - 20; src = ck; row0 = (g >> 1) * 32; colw = 32; coloff = (g & 1) * 16; }
    else if (f < 34) { src = gk; row0 = 160; colw = 64; coloff = (f - 30) * 16; }
    else             { src = ck; row0 = 160; colw = 32; coloff = (f - 34) * 16; }
  } else {
    if (f < 12)      { src = gk; row0 = (f >> 2) * 32; colw = 64; coloff = (f & 3) * 16; }
    else             { int g = f - 12; src = ck; row0 = (g >> 1) * 32; colw = 32; coloff = (g & 1) * 16; }
  }
  short8 v;
#pragma unroll
  for (int j = 0; j < 8; ++j)
    v[j] = (short)src[(row0 + q * 8 + j) * colw + coloff + nl];
  wf[frag * 64 + lane] = __builtin_bit_cast(uint4, v);
}

// ---------------------------------------------------------------------------
// ktypmax: masked type-embedding max, fully parallel (validated r11/r12).
// ---------------------------------------------------------------------------
__global__ __launch_bounds__(256) void ktypmax(
    const void* __restrict__ slot_tb, const void* __restrict__ slot_mb,
    const void* __restrict__ slot_ta, const void* __restrict__ slot_ma,
    const ushort_t* __restrict__ cvt, uint4* __restrict__ typf,
    const int* __restrict__ flags) {
  const int wv = threadIdx.x >> 6;
  const int lane = threadIdx.x & 63;
  const int q = lane >> 4, nl = lane & 15;
  const int job = blockIdx.x * 4 + wv;           // [0, 10240)
  const int st = job >> 9;                       // 0..19  (side*10+ts)
  const int btile = job & 511;
  const int side = (st >= 10) ? 1 : 0;
  const int ts = st - side * 10;
  const int b = btile * 16 + nl;
  const int sw = flags[2];
  const int bytem = flags[1];
  const int* tys = side ? (const int*)(sw ? slot_ma : slot_ta)
                        : (const int*)(sw ? slot_mb : slot_tb);
  const void* msk = side ? (sw ? slot_ta : slot_ma)
                         : (sw ? slot_tb : slot_mb);
  const int base = (b * 10 + ts) * 10;
  float mx[8];
#pragma unroll
  for (int j = 0; j < 8; ++j) mx[j] = -1e30f;
#pragma unroll
  for (int nt = 0; nt < 10; ++nt) {
    const int ty = tys[base + nt];
    const bool mv = bytem ? (((const unsigned char*)msk)[base + nt] != 0)
                          : (((const unsigned*)msk)[base + nt] != 0u);
    const float pen = mv ? 0.f : -1000.f;
    uint4 e = *reinterpret_cast<const uint4*>(cvt + U_TYPEMB + (size_t)ty * 32 + q * 8);
    const unsigned w[4] = {e.x, e.y, e.z, e.w};
#pragma unroll
    for (int j2 = 0; j2 < 4; ++j2) {
      mx[2 * j2]     = fmaxf(mx[2 * j2],     bf2f(w[j2] & 0xffffu) + pen);
      mx[2 * j2 + 1] = fmaxf(mx[2 * j2 + 1], bf2f(w[j2] >> 16) + pen);
    }
  }
  short8 v;
#pragma unroll
  for (int j = 0; j < 8; ++j) v[j] = (short)f2bf(mx[j]);
  typf[(size_t)job * 64 + lane] = __builtin_bit_cast(uint4, v);
}

// ---------------------------------------------------------------------------
// x-gather for 8-row jobs: token-embedding frags + typf element at
// (tile Rc>>4, slot Rc&15).
// ---------------------------------------------------------------------------
__device__ __forceinline__ void gatherX8(
    int t, int Rc, int q,
    const int* __restrict__ tok_b, const int* __restrict__ tok_a,
    const ushort_t* __restrict__ cvt, const uint4* __restrict__ typf,
    short8 af[5]) {
  if (t == 10) {
#pragma unroll
    for (int kt = 0; kt < 5; ++kt)
      af[kt] = __builtin_bit_cast(short8,
          *reinterpret_cast<const uint4*>(cvt + U_HOLE + kt * 32 + q * 8));
    return;
  }
  const int ts = (t < 10) ? t : t - 11;
  const int side = (t < 10) ? 0 : 1;
  const int tok = (side ? tok_a : tok_b)[Rc * 10 + ts];
#pragma unroll
  for (int kt = 0; kt < 4; ++kt)
    af[kt] = __builtin_bit_cast(short8,
        *reinterpret_cast<const uint4*>(cvt + U_TOKEMB + (size_t)tok * 128 + kt * 32 + q * 8));
  af[4] = __builtin_bit_cast(short8,
      typf[((size_t)(side * 10 + ts) * 512 + (Rc >> 4)) * 64 + q * 16 + (Rc & 15)]);
}

// ---------------------------------------------------------------------------
// krec0: layer-0 fused projection+recurrence, 8-row overlapped jobs.
// 2048 wave-jobs (1024 8-row tiles x 2 dirs) = 2 waves/SIMD. Wave computes
// padded rows 8jb..8jb+15 (reads clamped), stores only nl<8 rows into the
// 16-row y0a tile jb>>1 at slot nl+8*(jb&1). No barriers.
// ---------------------------------------------------------------------------
__global__ __launch_bounds__(256, 2) void krec0(
    const int* __restrict__ tok_b, const int* __restrict__ tok_a,
    const ushort_t* __restrict__ cvt, const uint4* __restrict__ wf,
    const uint4* __restrict__ typf, uint4* __restrict__ y0a) {
  __shared__ __align__(16) ushort_t hbuf[4][2][16 * 40];
  const int wv = threadIdx.x >> 6;
  const int lane = threadIdx.x & 63;
  const int q = lane >> 4, nl = lane & 15;
  const int job = blockIdx.x * 4 + wv;     // [0, 2048)
  const int dir = job & 1, jb = job >> 1;  // 8-row tile [0, 1024)
  const int R = jb * 8 + nl;
  const int Rc = (R < 8191) ? R : 8191;    // clamped read row

  const uint4* wfL0 = wf + dir * 36 * 64;
  short8 wg[5][4], wc[5][2], wgh[4], wch[2];
#pragma unroll
  for (int kt = 0; kt < 5; ++kt) {
#pragma unroll
    for (int tn = 0; tn < 4; ++tn)
      wg[kt][tn] = __builtin_bit_cast(short8, wfL0[(kt * 4 + tn) * 64 + lane]);
#pragma unroll
    for (int tn = 0; tn < 2; ++tn)
      wc[kt][tn] = __builtin_bit_cast(short8, wfL0[(20 + kt * 2 + tn) * 64 + lane]);
  }
#pragma unroll
  for (int tn = 0; tn < 4; ++tn)
    wgh[tn] = __builtin_bit_cast(short8, wfL0[(30 + tn) * 64 + lane]);
#pragma unroll
  for (int tn = 0; tn < 2; ++tn)
    wch[tn] = __builtin_bit_cast(short8, wfL0[(34 + tn) * 64 + lane]);

  const ushort_t* gb = cvt + (dir ? U_GBBW0 : U_GBFW0);
  const ushort_t* cb = cvt + (dir ? U_CBBW0 : U_CBFW0);
  float gb4[4], cb4[2];
#pragma unroll
  for (int tn = 0; tn < 4; ++tn) gb4[tn] = bf2f((unsigned)gb[tn * 16 + nl]);
#pragma unroll
  for (int tn = 0; tn < 2; ++tn) cb4[tn] = bf2f((unsigned)cb[tn * 16 + nl]);

  f32x4 hc0 = {0.f, 0.f, 0.f, 0.f}, hc1 = {0.f, 0.f, 0.f, 0.f};
  short8 hA = {0, 0, 0, 0, 0, 0, 0, 0};
  ushort_t* hb0 = hbuf[wv][0];
  ushort_t* hb1 = hbuf[wv][1];

  const int stile = jb >> 1;               // y0a 16-row tile
  const int sslot = nl + 8 * (jb & 1);     // slot within tile (for nl<8)

  short8 afc[5], afn[5];
  gatherX8(dir ? 20 : 0, Rc, q, tok_b, tok_a, cvt, typf, afc);

  for (int s = 0; s < 21; ++s) {
    const int t = dir ? 20 - s : s;
    if (s < 20)
      gatherX8(dir ? t - 1 : t + 1, Rc, q, tok_b, tok_a, cvt, typf, afn);

    // gates
    f32x4 ru[4];
#pragma unroll
    for (int tn = 0; tn < 4; ++tn) {
      f32x4 acc = {gb4[tn], gb4[tn], gb4[tn], gb4[tn]};
#pragma unroll
      for (int kt = 0; kt < 5; ++kt) acc = mfma16(afc[kt], wg[kt][tn], acc);
      acc = mfma16(hA, wgh[tn], acc);
      ru[tn] = acc;
    }
#pragma unroll
    for (int tn = 0; tn < 4; ++tn)
#pragma unroll
      for (int r = 0; r < 4; ++r) ru[tn][r] = sgm(ru[tn][r]);

    // r*h -> A-layout via per-wave LDS (no barrier)
#pragma unroll
    for (int r = 0; r < 4; ++r) {
      hb0[(q * 4 + r) * 40 + nl]      = f2bf(ru[0][r] * hc0[r]);
      hb0[(q * 4 + r) * 40 + 16 + nl] = f2bf(ru[1][r] * hc1[r]);
    }
    short8 rhA = *reinterpret_cast<const short8*>(hb0 + nl * 40 + q * 8);

    // candidate
    f32x4 cc0 = {cb4[0], cb4[0], cb4[0], cb4[0]};
    f32x4 cc1 = {cb4[1], cb4[1], cb4[1], cb4[1]};
#pragma unroll
    for (int kt = 0; kt < 5; ++kt) {
      cc0 = mfma16(afc[kt], wc[kt][0], cc0);
      cc1 = mfma16(afc[kt], wc[kt][1], cc1);
    }
    cc0 = mfma16(rhA, wch[0], cc0);
    cc1 = mfma16(rhA, wch[1], cc1);
#pragma unroll
    for (int r = 0; r < 4; ++r) {
      const float c0 = tnh(cc0[r]), c1 = tnh(cc1[r]);
      const float u0 = ru[2][r], u1 = ru[3][r];
      hc0[r] = u0 * hc0[r] + (1.f - u0) * c0;
      hc1[r] = u1 * hc1[r] + (1.f - u1) * c1;
    }

    // h' -> A-layout
#pragma unroll
    for (int r = 0; r < 4; ++r) {
      hb1[(q * 4 + r) * 40 + nl]      = f2bf(hc0[r]);
      hb1[(q * 4 + r) * 40 + 16 + nl] = f2bf(hc1[r]);
    }
    hA = *reinterpret_cast<const short8*>(hb1 + nl * 40 + q * 8);
    if (nl < 8)
      y0a[((size_t)(t * 512 + stile) * 2 + dir) * 64 + q * 16 + sslot] =
          __builtin_bit_cast(uint4, hA);

    if (s < 20) {
#pragma unroll
      for (int kt = 0; kt < 5; ++kt) afc[kt] = afn[kt];
    }
  }
}

// ---------------------------------------------------------------------------
// k3b: layer-1 recurrence, 8-row overlapped jobs + pipelined y-partials (r15).
// Reads y0a per-lane from tile Rc>>4 slot Rc&15; writes rows q<2 only.
// FP32 output [b][21][64].
// ---------------------------------------------------------------------------
__global__ __launch_bounds__(256, 2) void k3b(
    const ushort_t* __restrict__ cvt, const uint4* __restrict__ wf,
    const uint4* __restrict__ y0a, float* __restrict__ out) {
  __shared__ __align__(16) ushort_t hbuf[4][2][16 * 40];
  const int wv = threadIdx.x >> 6;
  const int lane = threadIdx.x & 63;
  const int q = lane >> 4, nl = lane & 15;
  const int job = blockIdx.x * 4 + wv;     // [0, 2048)
  const int dir = job & 1, jb = job >> 1;
  const int R = jb * 8 + nl;
  const int Rc = (R < 8191) ? R : 8191;
  const int rt = Rc >> 4, rs = Rc & 15;    // y0a read tile/slot

  const uint4* wfL1 = wf + (72 + dir * 18) * 64;
  short8 wgx0[4], wgx1[4], wgh[4], wcx0[2], wcx1[2], wch[2];
#pragma unroll
  for (int tn = 0; tn < 4; ++tn) {
    wgx0[tn] = __builtin_bit_cast(short8, wfL1[tn * 64 + lane]);
    wgx1[tn] = __builtin_bit_cast(short8, wfL1[(4 + tn) * 64 + lane]);
    wgh[tn]  = __builtin_bit_cast(short8, wfL1[(8 + tn) * 64 + lane]);
  }
#pragma unroll
  for (int tn = 0; tn < 2; ++tn) {
    wcx0[tn] = __builtin_bit_cast(short8, wfL1[(12 + tn) * 64 + lane]);
    wcx1[tn] = __builtin_bit_cast(short8, wfL1[(14 + tn) * 64 + lane]);
    wch[tn]  = __builtin_bit_cast(short8, wfL1[(16 + tn) * 64 + lane]);
  }
  const ushort_t* gb = cvt + (dir ? U_GBBW1 : U_GBFW1);
  const ushort_t* cb = cvt + (dir ? U_CBBW1 : U_CBFW1);
  float gb4[4], cb4[2];
#pragma unroll
  for (int tn = 0; tn < 4; ++tn) gb4[tn] = bf2f((unsigned)gb[tn * 16 + nl]);
#pragma unroll
  for (int tn = 0; tn < 2; ++tn) cb4[tn] = bf2f((unsigned)cb[tn * 16 + nl]);

  f32x4 hc0 = {0.f, 0.f, 0.f, 0.f}, hc1 = {0.f, 0.f, 0.f, 0.f};
  short8 hA = {0, 0, 0, 0, 0, 0, 0, 0};
  ushort_t* hb0 = hbuf[wv][0];
  ushort_t* hb1 = hbuf[wv][1];

#define LOAD_YA(tt, d0, d1)                                                      \
  do {                                                                           \
    d0 = __builtin_bit_cast(short8,                                              \
        y0a[((size_t)((tt) * 512 + rt) * 2 + 0) * 64 + q * 16 + rs]);            \
    d1 = __builtin_bit_cast(short8,                                              \
        y0a[((size_t)((tt) * 512 + rt) * 2 + 1) * 64 + q * 16 + rs]);            \
  } while (0)

  f32x4 px[6];
  {
    const int t0 = dir ? 20 : 0;
    short8 ya0, ya1;
    LOAD_YA(t0, ya0, ya1);
#pragma unroll
    for (int tn = 0; tn < 4; ++tn) {
      f32x4 acc = {gb4[tn], gb4[tn], gb4[tn], gb4[tn]};
      acc = mfma16(ya0, wgx0[tn], acc);
      acc = mfma16(ya1, wgx1[tn], acc);
      px[tn] = acc;
    }
#pragma unroll
    for (int tn = 0; tn < 2; ++tn) {
      f32x4 acc = {cb4[tn], cb4[tn], cb4[tn], cb4[tn]};
      acc = mfma16(ya0, wcx0[tn], acc);
      acc = mfma16(ya1, wcx1[tn], acc);
      px[4 + tn] = acc;
    }
  }

  for (int s = 0; s < 21; ++s) {
    const int t = dir ? 20 - s : s;

    short8 yn0, yn1;
    if (s < 20) LOAD_YA(dir ? t - 1 : t + 1, yn0, yn1);

    // ---- critical path ----
    f32x4 ru[4];
#pragma unroll
    for (int tn = 0; tn < 4; ++tn) ru[tn] = mfma16(hA, wgh[tn], px[tn]);
#pragma unroll
    for (int tn = 0; tn < 4; ++tn)
#pragma unroll
      for (int r = 0; r < 4; ++r) ru[tn][r] = sgm(ru[tn][r]);

#pragma unroll
    for (int r = 0; r < 4; ++r) {
      hb0[(q * 4 + r) * 40 + nl]      = f2bf(ru[0][r] * hc0[r]);
      hb0[(q * 4 + r) * 40 + 16 + nl] = f2bf(ru[1][r] * hc1[r]);
    }
    short8 rhA = *reinterpret_cast<const short8*>(hb0 + nl * 40 + q * 8);

    f32x4 cc0 = mfma16(rhA, wch[0], px[4]);
    f32x4 cc1 = mfma16(rhA, wch[1], px[5]);
#pragma unroll
    for (int r = 0; r < 4; ++r) {
      const float c0 = tnh(cc0[r]), c1 = tnh(cc1[r]);
      const float u0 = ru[2][r], u1 = ru[3][r];
      hc0[r] = u0 * hc0[r] + (1.f - u0) * c0;
      hc1[r] = u1 * hc1[r] + (1.f - u1) * c1;
    }

#pragma unroll
    for (int r = 0; r < 4; ++r) {
      hb1[(q * 4 + r) * 40 + nl]      = f2bf(hc0[r]);
      hb1[(q * 4 + r) * 40 + 16 + nl] = f2bf(hc1[r]);
    }
    hA = *reinterpret_cast<const short8*>(hb1 + nl * 40 + q * 8);

    // FP32 output: only this wave's low 8 padded rows (q<2)
    if (q < 2) {
#pragma unroll
      for (int r = 0; r < 4; ++r) {
        const size_t o = ((size_t)(jb * 8 + q * 4 + r) * 21 + t) * 64 + dir * 32 + nl;
        out[o]      = hc0[r];
        out[o + 16] = hc1[r];
      }
    }

    // ---- pipeline: next step's y-partials ----
    if (s < 20) {
#pragma unroll
      for (int tn = 0; tn < 4; ++tn) {
        f32x4 acc = {gb4[tn], gb4[tn], gb4[tn], gb4[tn]};
        acc = mfma16(yn0, wgx0[tn], acc);
        acc = mfma16(yn1, wgx1[tn], acc);
        px[tn] = acc;
      }
#pragma unroll
      for (int tn = 0; tn < 2; ++tn) {
        f32x4 acc = {cb4[tn], cb4[tn], cb4[tn], cb4[tn]};
        acc = mfma16(yn0, wcx0[tn], acc);
        acc = mfma16(yn1, wcx1[tn], acc);
        px[4 + tn] = acc;
      }
    }
  }
#undef LOAD_YA
}

// ---------------------------------------------------------------------------
extern "C" void kernel_launch(void* const* d_in, const int* in_sizes, int n_in,
                              void* d_out, int out_size, void* d_ws, size_t ws_size,
                              hipStream_t stream)
{
  const int* tok_b = (const int*)d_in[0];
  const void* slot_tb = d_in[1];
  const void* slot_mb = d_in[2];
  const int* tok_a = (const int*)d_in[3];
  const void* slot_ta = d_in[4];
  const void* slot_ma = d_in[5];

  int* flags = (int*)d_ws;
  ushort_t* cvt = (ushort_t*)((char*)d_ws + 64);
  uint4* y0a = (uint4*)((char*)d_ws + Y0A_OFF);
  uint4* typf = (uint4*)((char*)d_ws + TYPF_OFF);
  uint4* wf  = (uint4*)((char*)d_ws + WF_OFF);

  k0_detect<<<dim3(1), dim3(64), 0, stream>>>(
      (const ushort_t*)d_in[6], (const unsigned*)slot_mb, (const unsigned*)slot_tb,
      flags);

  static const int slen[19] = {640000, 160000, 160,
                               12288, 64, 6144, 32, 12288, 64, 6144, 32,
                               6144, 64, 3072, 32, 6144, 64, 3072, 32};
  static const int sdst[19] = {U_TOKEMB, U_TYPEMB, U_HOLE,
                               U_GKFW0, U_GBFW0, U_CKFW0, U_CBFW0,
                               U_GKBW0, U_GBBW0, U_CKBW0, U_CBBW0,
                               U_GKFW1, U_GBFW1, U_CKFW1, U_CBFW1,
                               U_GKBW1, U_GBBW1, U_CKBW1, U_CBBW1};
  Cvt19 a;
  int tot = 0;
  for (int i = 0; i < 19; ++i) {
    a.src[i] = d_in[6 + i]; a.len[i] = slen[i]; a.dst[i] = sdst[i]; tot += slen[i];
  }
  kcvt<<<dim3((tot + 255) / 256), dim3(256), 0, stream>>>(a, cvt, flags);

  kswz<<<dim3(27), dim3(256), 0, stream>>>(cvt, wf);

  ktypmax<<<dim3(2560), dim3(256), 0, stream>>>(
      slot_tb, slot_mb, slot_ta, slot_ma, cvt, typf, flags);

  krec0<<<dim3(512), dim3(256), 0, stream>>>(tok_b, tok_a, cvt, wf, typf, y0a);

  k3b<<<dim3(512), dim3(256), 0, stream>>>(cvt, wf, y0a, (float*)d_out);
}